// Round 9
// baseline (220.414 us; speedup 1.0000x reference)
//
#include <hip/hip_runtime.h>

#define BB 8
#define NN 2048
#define CC 128
#define KMAX 32
#define NEG 0.2f
#define CH 8
#define CHSZ (NN / CH)   // 256
#define CAP 32           // per-thread candidate buffer (u8 entries; drain-on-full keeps j order)

using bf16x8 = __attribute__((ext_vector_type(8))) short;  // 8 bf16 (4 VGPRs)
using f32x4  = __attribute__((ext_vector_type(4))) float;  // 4 fp32

// Map f32 to a u32 whose unsigned order == float order (handles negatives).
__device__ __forceinline__ unsigned int f2key(float f) {
  unsigned int b = __float_as_uint(f);
  return (b & 0x80000000u) ? ~b : (b | 0x80000000u);
}

// np-exact f32 squared norm: fl(fl(x^2+y^2)+z^2), no FMA contraction.
__device__ __forceinline__ float sq3(float x, float y, float z) {
  return __fadd_rn(__fadd_rn(__fmul_rn(x, x), __fmul_rn(y, y)), __fmul_rn(z, z));
}

// np-exact f32 distance key: d2 = fl( fl(sq_i+sq_j) - fl(2*dot) ).
__device__ __forceinline__ float d2np(float px, float py, float pz, float sqq,
                                      float qx, float qy, float qz, float sqj) {
  float dot = __fmaf_rn(pz, qz, __fmaf_rn(py, qy, __fmul_rn(px, qx)));
  return __fsub_rn(__fadd_rn(sqq, sqj), __fmul_rn(2.0f, dot));
}

// f32 -> bf16 (round to nearest even), finite inputs.
__device__ __forceinline__ unsigned short f2bf(float f) {
  unsigned int u = __float_as_uint(f);
  return (unsigned short)((u + 0x7fffu + ((u >> 16) & 1u)) >> 16);
}
// bf16 -> f32, exact.
__device__ __forceinline__ float bf2f(unsigned short u) {
  return __uint_as_float(((unsigned int)u) << 16);
}

// 8 consecutive f32 -> bf16x8 A-fragment (bit-identical to the old cvt_x+load).
__device__ __forceinline__ bf16x8 cvt8(const float* __restrict__ p) {
  float4 a = *(const float4*)(p);
  float4 b = *(const float4*)(p + 4);
  bf16x8 r;
  r[0] = (short)f2bf(a.x); r[1] = (short)f2bf(a.y);
  r[2] = (short)f2bf(a.z); r[3] = (short)f2bf(a.w);
  r[4] = (short)f2bf(b.x); r[5] = (short)f2bf(b.y);
  r[6] = (short)f2bf(b.z); r[7] = (short)f2bf(b.w);
  return r;
}

// XOR-swizzled LDS slot for point (chunk c, offset jj). Conflict-free for the
// 8-address broadcast pattern: bank quad = 4*((jj^c)&7), distinct over c.
__device__ __forceinline__ int paddr(int c, int jj) { return (c << 8) + (jj ^ c); }

// ---------------------------------------------------------------------------
// knn_p1 body (R2-proven, ff=66.9us measured twice): CH=8, LDS sp4 cache,
// keep-4 float network, shfl T, drain with np-exact f2key keys, global
// cand/candk writes. In-block merge removed (R7/R8 proved it costs ~23us
// vs ~5-9us for the separate p2 kernel — serial dependent-LDS chain).
// ---------------------------------------------------------------------------
__device__ __forceinline__ void knn_body(int bx, int tid,
                                         const float* __restrict__ pos,
                                         unsigned short* __restrict__ cand,
                                         unsigned int* __restrict__ candk,
                                         float4* __restrict__ sp4,
                                         unsigned char* __restrict__ sbuf) {
  int b = bx >> 6;                               // 64 blocks per batch
  int qbase = (bx & 63) * 32;
  const float* pb = pos + (size_t)b * NN * 3;
  for (int t = tid; t < NN; t += 256) {
    float xx = pb[t * 3 + 0];
    float yy = pb[t * 3 + 1];
    float zz = pb[t * 3 + 2];
    sp4[paddr(t >> 8, t & 255)] = make_float4(xx, yy, zz, sq3(xx, yy, zz));
  }
  __syncthreads();

  int q = qbase + (tid >> 3);
  int c = tid & 7;
  float4 pq = sp4[paddr(q >> 8, q & 255)];
  float px = pq.x, py = pq.y, pz = pq.z;
  float sqq = pq.w;
  int j0 = c * CHSZ;

  // ---- pass 1: per-chunk 4th-best via min/max insertion network (values only)
  const float SENT = 3.0e38f;                    // loses to every real d2
  float a0 = SENT, a1 = SENT, a2 = SENT, a3 = SENT;
#pragma unroll 4
  for (int jj = 0; jj < CHSZ; ++jj) {
    float4 pj = sp4[paddr(c, jj)];               // one ds_read_b128, 8-addr broadcast
    float d2 = d2np(px, py, pz, sqq, pj.x, pj.y, pj.z, pj.w);
    if (j0 + jj == q) d2 = SENT;                 // self never competes
    float m0 = fmaxf(a0, d2); a0 = fminf(a0, d2);
    float m1 = fmaxf(a1, m0); a1 = fminf(a1, m0);
    float m2 = fmaxf(a2, m1); a2 = fminf(a2, m1);
    a3 = fminf(a3, m2);
  }

  // ---- threshold: max of 4th-best over the 8 chunks of this query (intra-wave)
  float T = a3;
  T = fmaxf(T, __shfl_xor(T, 1));
  T = fmaxf(T, __shfl_xor(T, 2));
  T = fmaxf(T, __shfl_xor(T, 4));

  unsigned int ak[KMAX];
  int ai[KMAX];
#pragma unroll
  for (int k = 0; k < KMAX; ++k) { ak[k] = 0xFFFFFFFFu; ai[k] = 0xFFFF; }

  int sbase = tid * CAP;
  auto drain = [&](int cnt2) {
    for (int u = 0; u < cnt2; ++u) {
      int jj2 = (int)sbuf[sbase + u];
      int j = j0 + jj2;
      float4 pj = sp4[paddr(c, jj2)];
      float d2 = d2np(px, py, pz, sqq, pj.x, pj.y, pj.z, pj.w);
      unsigned int key = f2key(d2);               // self never buffered
      if (key < ak[KMAX - 1]) {                   // strict: stable ties -> lower j
#pragma unroll
        for (int k = KMAX - 1; k >= 1; --k) {
          bool ck  = key < ak[k];
          bool ckm = key < ak[k - 1];
          unsigned int tk = ckm ? ak[k - 1] : key;
          int          ti = ckm ? ai[k - 1] : j;
          ak[k] = ck ? tk : ak[k];
          ai[k] = ck ? ti : ai[k];
        }
        bool c0b = key < ak[0];
        ak[0] = c0b ? key : ak[0];
        ai[0] = c0b ? j : ai[0];
      }
    }
  };

  // ---- pass 2: gate d2 <= T (monotone-equivalent to key <= T_key), buffer jj
  int cnt = 0;
  for (int jj = 0; jj < CHSZ; ++jj) {
    float4 pj = sp4[paddr(c, jj)];
    float d2 = d2np(px, py, pz, sqq, pj.x, pj.y, pj.z, pj.w);
    bool pass = (d2 <= T) && (j0 + jj != q);
    if (pass) {
      if (cnt == CAP) { drain(CAP); cnt = 0; }   // rare; preserves j order
      sbuf[sbase + cnt] = (unsigned char)jj;
      ++cnt;
    }
  }
  drain(cnt);

  size_t obase = (((size_t)(b * NN + q)) * CH + c) * KMAX;
  unsigned short* oc = cand + obase;
  unsigned int* ok = candk + obase;
#pragma unroll
  for (int k = 0; k < KMAX; ++k) {
    oc[k] = (unsigned short)ai[k];
    ok[k] = ak[k];
  }
}

// ---------------------------------------------------------------------------
// 6-proj MFMA body (on-the-fly x conversion), bf16 out.
// ---------------------------------------------------------------------------
__device__ __forceinline__ void proj_body(int z, int mx, int tid,
                                          const float* __restrict__ x,
                                          const unsigned short* __restrict__ wf,
                                          unsigned short* __restrict__ projb) {
  unsigned short* out = projb + (size_t)z * ((size_t)BB * NN * CC);
  int wave = tid >> 6;
  int lane = tid & 63;
  int m0 = (mx * 4 + wave) * 16;
  int quad = lane >> 4;
  int am = m0 + (lane & 15);

  f32x4 acc[8];
#pragma unroll
  for (int nt = 0; nt < 8; ++nt) acc[nt] = (f32x4){0.f, 0.f, 0.f, 0.f};

  const unsigned short* wz = wf + (size_t)z * (8 * 4 * 64 * 8);
#pragma unroll
  for (int ks = 0; ks < 4; ++ks) {
    bf16x8 a = cvt8(x + (size_t)am * CC + ks * 32 + quad * 8);
#pragma unroll
    for (int nt = 0; nt < 8; ++nt) {
      bf16x8 bfr = *(const bf16x8*)(wz + (size_t)(((nt * 4 + ks) * 64 + lane) * 8));
      acc[nt] = __builtin_amdgcn_mfma_f32_16x16x32_bf16(a, bfr, acc[nt], 0, 0, 0);
    }
  }

  int col0 = lane & 15;
#pragma unroll
  for (int nt = 0; nt < 8; ++nt)
#pragma unroll
    for (int r = 0; r < 4; ++r)
      out[(size_t)(m0 + quad * 4 + r) * CC + nt * 16 + col0] = f2bf(acc[nt][r]);
}

// ---------------------------------------------------------------------------
// Wg epilogue MFMA body (on-the-fly x conversion), f32 h out.
// ---------------------------------------------------------------------------
__device__ __forceinline__ void wg_body(int mx, int tid,
                                        const float* __restrict__ x,
                                        const float* __restrict__ pos,
                                        const unsigned short* __restrict__ wf,
                                        const float* __restrict__ wgtail,
                                        const float* __restrict__ bg,
                                        float* __restrict__ h) {
  int wave = tid >> 6;
  int lane = tid & 63;
  int m0 = (mx * 4 + wave) * 16;
  int quad = lane >> 4;
  int am = m0 + (lane & 15);

  f32x4 acc[8];
#pragma unroll
  for (int nt = 0; nt < 8; ++nt) acc[nt] = (f32x4){0.f, 0.f, 0.f, 0.f};

  const unsigned short* wz = wf + (size_t)6 * (8 * 4 * 64 * 8);
#pragma unroll
  for (int ks = 0; ks < 4; ++ks) {
    bf16x8 a = cvt8(x + (size_t)am * CC + ks * 32 + quad * 8);
#pragma unroll
    for (int nt = 0; nt < 8; ++nt) {
      bf16x8 b = *(const bf16x8*)(wz + (size_t)(((nt * 4 + ks) * 64 + lane) * 8));
      acc[nt] = __builtin_amdgcn_mfma_f32_16x16x32_bf16(a, b, acc[nt], 0, 0, 0);
    }
  }

  float posr[4][3];
#pragma unroll
  for (int r = 0; r < 4; ++r) {
    int m = m0 + quad * 4 + r;
    posr[r][0] = pos[m * 3 + 0];
    posr[r][1] = pos[m * 3 + 1];
    posr[r][2] = pos[m * 3 + 2];
  }

  int col0 = lane & 15;
#pragma unroll
  for (int nt = 0; nt < 8; ++nt) {
    int col = nt * 16 + col0;
    float bv = bg[col];
    float t0 = wgtail[col];
    float t1 = wgtail[CC + col];
    float t2 = wgtail[2 * CC + col];
#pragma unroll
    for (int r = 0; r < 4; ++r) {
      float v = acc[nt][r] + bv
              + posr[r][0] * t0 + posr[r][1] * t1 + posr[r][2] * t2;
      v = v > 0.f ? v : NEG * v;
      h[(size_t)(m0 + quad * 4 + r) * CC + col] = v;
    }
  }
}

// ---------------------------------------------------------------------------
// FUSED FRONT: blocks [0,512) = knn_p1; [512,2048) = 6-proj; [2048,2304) = Wg.
// LDS exactly 40,960 B (R2-proven config, ff = 66.9us).
// ---------------------------------------------------------------------------
__global__ __launch_bounds__(256) void fused_front(
    const float* __restrict__ pos,
    unsigned short* __restrict__ cand,
    unsigned int* __restrict__ candk,
    const float* __restrict__ x,
    const unsigned short* __restrict__ wf,
    unsigned short* __restrict__ projb,
    const float* __restrict__ wgtail,
    const float* __restrict__ bg,
    float* __restrict__ h) {
  __shared__ float4 sp4[CH * 256];               // 32,768 B (XOR-swizzled)
  __shared__ unsigned char sbuf[256 * CAP];      // 8,192 B

  if (blockIdx.x < 512) {
    knn_body(blockIdx.x, threadIdx.x, pos, cand, candk, sp4, sbuf);
  } else if (blockIdx.x < 2048) {
    int bx = blockIdx.x - 512;
    proj_body(bx >> 8, bx & 255, threadIdx.x, x, wf, projb);
  } else {
    wg_body(blockIdx.x - 2048, threadIdx.x, x, pos, wf, wgtail, bg, h);
  }
}

// ---------------------------------------------------------------------------
// K1a (fallback only): knn_p1 standalone — same body.
// ---------------------------------------------------------------------------
__global__ __launch_bounds__(256) void knn_p1(const float* __restrict__ pos,
                                              unsigned short* __restrict__ cand,
                                              unsigned int* __restrict__ candk) {
  __shared__ float4 sp4[CH * 256];
  __shared__ unsigned char sbuf[256 * CAP];
  knn_body(blockIdx.x, threadIdx.x, pos, cand, candk, sp4, sbuf);
}

// ---------------------------------------------------------------------------
// K1b: KNN phase 2 — 8-way merge. FROZEN R9-lineage bytes (proven).
// ---------------------------------------------------------------------------
__global__ __launch_bounds__(64) void knn_p2(const unsigned int* __restrict__ candk,
                                             const unsigned short* __restrict__ cand,
                                             int* __restrict__ nbr) {
  int q = blockIdx.x * 64 + threadIdx.x;         // global query id (b*NN+n)
  const unsigned int* k8 = candk + (size_t)q * (CH * KMAX);
  const unsigned short* i8 = cand + (size_t)q * (CH * KMAX);

  int head[CH];
  unsigned int hk[CH];
#pragma unroll
  for (int c = 0; c < CH; ++c) {
    head[c] = 0;
    hk[c] = k8[c * KMAX];
  }

  int* onb = nbr + (size_t)q * KMAX;
#pragma unroll
  for (int r = 0; r < KMAX; ++r) {
    int bc = 0;
    unsigned int bk = hk[0];
#pragma unroll
    for (int c = 1; c < CH; ++c) {
      if (hk[c] < bk) { bk = hk[c]; bc = c; }    // strict: ties -> lower c = lower j
    }
    onb[r] = (int)i8[bc * KMAX + head[bc]];
    ++head[bc];
    hk[bc] = (head[bc] < KMAX) ? k8[bc * KMAX + head[bc]] : 0xFFFFFFFFu;
  }
}

// ---------------------------------------------------------------------------
// K-wcvt: blocks [0,64): 8 weight matrices (f32) -> bf16 B-fragment order.
// Blocks [64,192): pos-projection pp[l][m][c] = pos_m . Wpos[l][:,c] (f32).
// ---------------------------------------------------------------------------
__global__ __launch_bounds__(256) void wcvt(const float* __restrict__ Wa,
                                            const float* __restrict__ Wb,
                                            const float* __restrict__ Wc,
                                            const float* __restrict__ Wgm,
                                            const float* __restrict__ W1m,
                                            unsigned short* __restrict__ wf,
                                            const float* __restrict__ Wpos,
                                            const float* __restrict__ pos,
                                            float* __restrict__ pp) {
  if (blockIdx.x < 64) {
    int t = blockIdx.x * 256 + threadIdx.x;      // 0 .. 16383
    int lane = t & 63;
    int ks = (t >> 6) & 3;
    int nt = (t >> 8) & 7;
    int z = t >> 11;
    const float* W = (z < 2) ? (Wa + (size_t)z * CC * CC)
                   : (z < 4) ? (Wb + (size_t)(z - 2) * CC * CC)
                   : (z < 6) ? (Wc + (size_t)(z - 4) * CC * CC)
                   : (z == 6) ? Wgm : W1m;
    int n = nt * 16 + (lane & 15);
    int kb = ks * 32 + (lane >> 4) * 8;
    unsigned short* o = wf + (size_t)t * 8;
#pragma unroll
    for (int j = 0; j < 8; ++j)
      o[j] = f2bf(W[(size_t)(kb + j) * CC + n]);
  } else {
    int pb2 = blockIdx.x - 64;                   // 0..127 -> 128 m-rows each
    int l = threadIdx.x >> 7;                    // layer 0/1
    int c = threadIdx.x & 127;
    const float* Wp = Wpos + (size_t)l * 3 * CC;
    float w0 = Wp[c], w1 = Wp[CC + c], w2 = Wp[2 * CC + c];
    float* ppl = pp + (size_t)l * ((size_t)BB * NN * CC);
    int m0 = pb2 * 128;
    for (int mi = 0; mi < 128; ++mi) {
      int m = m0 + mi;
      float xx = pos[m * 3 + 0];
      float yy = pos[m * 3 + 1];
      float zz = pos[m * 3 + 2];
      ppl[(size_t)m * CC + c] = __fmaf_rn(zz, w2, __fmaf_rn(yy, w1, __fmul_rn(xx, w0)));
    }
  }
}

// ---------------------------------------------------------------------------
// Fallback-only standalone wrappers for the two MFMA bodies.
// ---------------------------------------------------------------------------
__global__ __launch_bounds__(256) void proj_fly(const float* __restrict__ x,
                                                const unsigned short* __restrict__ wf,
                                                unsigned short* __restrict__ projb) {
  proj_body(blockIdx.z, blockIdx.x, threadIdx.x, x, wf, projb);
}
__global__ __launch_bounds__(256) void wg_fly(const float* __restrict__ x,
                                              const float* __restrict__ pos,
                                              const unsigned short* __restrict__ wf,
                                              const float* __restrict__ wgtail,
                                              const float* __restrict__ bg,
                                              float* __restrict__ h) {
  wg_body(blockIdx.x, threadIdx.x, x, pos, wf, wgtail, bg, h);
}

// ---------------------------------------------------------------------------
// K3: fused attention v3 (R7/R8-proven) — delta via precomputed pos-projection
// pp: del = pp_i - pp_j + bp. Block 128 = one point's channels.
// ---------------------------------------------------------------------------
__global__ __launch_bounds__(128) void attn2_kernel(
    const int* __restrict__ nbr,
    const unsigned short* __restrict__ s0, const unsigned short* __restrict__ v0,
    const unsigned short* __restrict__ t0,
    const unsigned short* __restrict__ s1, const unsigned short* __restrict__ v1,
    const unsigned short* __restrict__ t1,
    const float* __restrict__ pp, const float* __restrict__ bpos,
    const float* __restrict__ h, unsigned short* __restrict__ hb) {
  int b = blockIdx.x & 7;                        // XCD-locality swizzle
  int n = blockIdx.x >> 3;
  int bn = (b << 11) + n;
  int c = threadIdx.x;

  // batched neighbor-row load: 32 ints = 8 x int4 (nbr rows are 128B-aligned)
  const int* nb = nbr + (size_t)bn * KMAX;
  int idxs[KMAX];
#pragma unroll
  for (int u = 0; u < KMAX / 4; ++u) {
    int4 v4 = *(const int4*)(nb + u * 4);
    idxs[u * 4 + 0] = v4.x; idxs[u * 4 + 1] = v4.y;
    idxs[u * 4 + 2] = v4.z; idxs[u * 4 + 3] = v4.w;
  }

  float ht = h[(size_t)bn * CC + c];             // h_in (Wg output, f32)

#pragma unroll
  for (int l = 0; l < 2; ++l) {
    int dil = l + 1;
    const unsigned short* s = l ? s1 : s0;
    const unsigned short* v = l ? v1 : v0;
    const unsigned short* t = l ? t1 : t0;
    const float* ppl = pp + (size_t)l * ((size_t)BB * NN * CC);
    float bp = bpos[(size_t)l * CC + c];
    float tc = bf2f(t[(size_t)bn * CC + c]);
    float ppi = ppl[(size_t)bn * CC + c];

    // neighbor ids for this layer (compile-time indices -> registers)
    int id[17];
#pragma unroll
    for (int j = 0; j < 17; ++j) id[j] = (j < 16) ? idxs[j * dil] : n;

    // batched independent gathers: s (bf16) and pp (f32), coalesced rows
    float sc[17], pj[17];
#pragma unroll
    for (int j = 0; j < 17; ++j)
      sc[j] = bf2f(s[((size_t)(b * NN + id[j])) * CC + c]);
#pragma unroll
    for (int j = 0; j < 17; ++j)
      pj[j] = ppl[((size_t)(b * NN + id[j])) * CC + c];

    float alpha[17], del[17];
#pragma unroll
    for (int j = 0; j < 17; ++j) {
      float d = ppi - pj[j] + bp;
      del[j] = d;
      alpha[j] = tc - sc[j] + d;
    }
    // fmax tree (associative & commutative on finite floats)
    float m8[8];
#pragma unroll
    for (int j = 0; j < 8; ++j) m8[j] = fmaxf(alpha[j], alpha[j + 8]);
    float m4a = fmaxf(m8[0], m8[1]), m4b = fmaxf(m8[2], m8[3]);
    float m4c = fmaxf(m8[4], m8[5]), m4d = fmaxf(m8[6], m8[7]);
    float mx = fmaxf(fmaxf(fmaxf(m4a, m4b), fmaxf(m4c, m4d)), alpha[16]);

    float sum = 0.f;
#pragma unroll
    for (int j = 0; j < 17; ++j) {
      float w = __expf(alpha[j] - mx);
      alpha[j] = w;
      sum += w;
    }
    float inv = 1.f / sum;

    // batched independent v-gathers
    float vc[17];
#pragma unroll
    for (int j = 0; j < 17; ++j)
      vc[j] = bf2f(v[((size_t)(b * NN + id[j])) * CC + c]);

    float hc = 0.f;
#pragma unroll
    for (int j = 0; j < 17; ++j)
      hc += alpha[j] * (vc[j] + del[j]);
    ht += hc * inv;
  }

  hb[(size_t)bn * CC + c] = f2bf(ht);
}

// ---------------------------------------------------------------------------
// K4: W1 MFMA + final projection fused. Grid M/64 x 256.
// ---------------------------------------------------------------------------
__global__ __launch_bounds__(256) void mfma_w1_final(
    const unsigned short* __restrict__ hb,
    const unsigned short* __restrict__ wz,
    const float* __restrict__ b1,
    const float* __restrict__ W2,
    const float* __restrict__ b2,
    const float* __restrict__ pos,
    float* __restrict__ out) {
  int wave = threadIdx.x >> 6;
  int lane = threadIdx.x & 63;
  int m0 = (blockIdx.x * 4 + wave) * 16;
  int quad = lane >> 4;
  int am = m0 + (lane & 15);

  f32x4 acc[8];
#pragma unroll
  for (int nt = 0; nt < 8; ++nt) acc[nt] = (f32x4){0.f, 0.f, 0.f, 0.f};

#pragma unroll
  for (int ks = 0; ks < 4; ++ks) {
    bf16x8 a = *(const bf16x8*)(hb + (size_t)am * CC + ks * 32 + quad * 8);
#pragma unroll
    for (int nt = 0; nt < 8; ++nt) {
      bf16x8 b = *(const bf16x8*)(wz + (size_t)(((nt * 4 + ks) * 64 + lane) * 8));
      acc[nt] = __builtin_amdgcn_mfma_f32_16x16x32_bf16(a, b, acc[nt], 0, 0, 0);
    }
  }

  int col0 = lane & 15;
  float part[4][3];
#pragma unroll
  for (int r = 0; r < 4; ++r)
#pragma unroll
    for (int d = 0; d < 3; ++d) part[r][d] = 0.f;

#pragma unroll
  for (int nt = 0; nt < 8; ++nt) {
    int col = nt * 16 + col0;
    float bv = b1[col];
    float w20 = W2[col * 3 + 0];
    float w21 = W2[col * 3 + 1];
    float w22 = W2[col * 3 + 2];
#pragma unroll
    for (int r = 0; r < 4; ++r) {
      float gv = acc[nt][r] + bv;
      gv = gv > 0.f ? gv : NEG * gv;
      part[r][0] = fmaf(gv, w20, part[r][0]);
      part[r][1] = fmaf(gv, w21, part[r][1]);
      part[r][2] = fmaf(gv, w22, part[r][2]);
    }
  }

#pragma unroll
  for (int off = 8; off >= 1; off >>= 1) {
#pragma unroll
    for (int r = 0; r < 4; ++r)
#pragma unroll
      for (int d = 0; d < 3; ++d)
        part[r][d] += __shfl_xor(part[r][d], off);
  }

  if (col0 == 0) {
#pragma unroll
    for (int r = 0; r < 4; ++r) {
      int m = m0 + quad * 4 + r;
#pragma unroll
      for (int d = 0; d < 3; ++d)
        out[(size_t)m * 3 + d] = part[r][d] + b2[d] + pos[(size_t)m * 3 + d];
    }
  }
}

extern "C" void kernel_launch(void* const* d_in, const int* in_sizes, int n_in,
                              void* d_out, int out_size, void* d_ws, size_t ws_size,
                              hipStream_t stream) {
  const float* x     = (const float*)d_in[0];
  const float* pos   = (const float*)d_in[1];
  const float* W_lin = (const float*)d_in[2];
  const float* W_src = (const float*)d_in[3];
  const float* W_dst = (const float*)d_in[4];
  const float* W_pos = (const float*)d_in[5];
  const float* b_pos = (const float*)d_in[6];
  const float* Wg    = (const float*)d_in[7];
  const float* bg    = (const float*)d_in[8];
  const float* W1    = (const float*)d_in[9];
  const float* b1    = (const float*)d_in[10];
  const float* W2    = (const float*)d_in[11];
  const float* b2    = (const float*)d_in[12];
  float* out = (float*)d_out;

  const size_t M = (size_t)BB * NN;        // 16384
  const size_t MC = M * CC;                // 2,097,152

  // Layout (proven offsets): nbr 2MB | cand 8.39MB | fb region:
  //   projb (bf16, fb[0..3MC))  s0,s1,v0,v1,t0,t1
  //   candk (u32,  fb[3MC..5MC))
  //   h     (f32,  fb[5MC..6MC))
  //   pp    (f32,  fb[6MC..8MC))  2 layers x M x C pos-projection
  // hb at ws+BASE (4MB) | wf at ws+BASE+4MB (256KB).
  char* ws = (char*)d_ws;
  int* nbr = (int*)ws;
  unsigned short* cand = (unsigned short*)(ws + M * KMAX * sizeof(int));
  float* fb = (float*)(ws + M * KMAX * sizeof(int) + M * CH * KMAX * sizeof(unsigned short));
  unsigned short* projb = (unsigned short*)fb;
  unsigned short* sb0 = projb + 0 * MC;
  unsigned short* sb1 = projb + 1 * MC;
  unsigned short* vb0 = projb + 2 * MC;
  unsigned short* vb1 = projb + 3 * MC;
  unsigned short* tb0 = projb + 4 * MC;
  unsigned short* tb1 = projb + 5 * MC;
  unsigned int* candk = (unsigned int*)(fb + 3 * MC);
  float* h = fb + 5 * MC;
  float* pp = fb + 6 * MC;                 // 16 MB pos-projection

  const size_t BASE = M * KMAX * sizeof(int) + M * CH * KMAX * sizeof(unsigned short)
                    + 8 * MC * sizeof(float);                 // proven offset
  const size_t XB_BYTES = MC * sizeof(unsigned short);        // 4 MB (hb slot)
  const size_t WF_BYTES = 8 * 16384 * sizeof(unsigned short); // 256 KB
  const size_t FRAG = (size_t)(8 * 4 * 64 * 8);               // bf16 elems per weight
  bool fused_ok = ws_size >= BASE + XB_BYTES + WF_BYTES;

  if (fused_ok) {
    unsigned short* hb = (unsigned short*)(ws + BASE);
    unsigned short* wf = (unsigned short*)(ws + BASE + XB_BYTES);

    // 1. weight fragments + pos-projection (one small kernel)
    wcvt<<<192, 256, 0, stream>>>(W_src, W_lin, W_dst, Wg, W1, wf, W_pos, pos, pp);
    // 2. knn_p1 [0,512) + 6-proj [512,2048) + Wg-epi [2048,2304)
    fused_front<<<2304, 256, 0, stream>>>(pos, cand, candk, x, wf, projb,
                                          Wg + 128 * CC, bg, h);
    // 3. merge (separate kernel: R7/R8 proved in-block merge costs ~23us vs this ~5-9us)
    knn_p2<<<256, 64, 0, stream>>>(candk, cand, nbr);
    // 4. attention (pp-based delta); writes hb = bf16(h_out)
    attn2_kernel<<<M, 128, 0, stream>>>(nbr, sb0, vb0, tb0,
                                        sb1, vb1, tb1, pp, b_pos, h, hb);
    // 5. g = leaky(h@W1+b1) via MFMA, then W2 reduce + b2 + pos, fused
    mfma_w1_final<<<M / 64, 256, 0, stream>>>(hb, wf + 7 * FRAG, b1,
                                              W2, b2, pos, out);
  } else {
    // Fallback: sequential, same numerics. hb/wf alias cand (dead after p2).
    unsigned short* hb = cand;
    unsigned short* wf = cand + MC;
    knn_p1<<<512, 256, 0, stream>>>(pos, cand, candk);
    knn_p2<<<256, 64, 0, stream>>>(candk, cand, nbr);
    wcvt<<<192, 256, 0, stream>>>(W_src, W_lin, W_dst, Wg, W1, wf, W_pos, pos, pp);
    proj_fly<<<dim3(256, 1, 6), 256, 0, stream>>>(x, wf, projb);
    wg_fly<<<256, 256, 0, stream>>>(x, pos, wf, Wg + 128 * CC, bg, h);
    attn2_kernel<<<M, 128, 0, stream>>>(nbr, sb0, vb0, tb0,
                                        sb1, vb1, tb1, pp, b_pos, h, hb);
    mfma_w1_final<<<M / 64, 256, 0, stream>>>(hb, wf + 7 * FRAG, b1,
                                              W2, b2, pos, out);
  }
}

// Round 10
// 196.790 us; speedup vs baseline: 1.1200x; 1.1200x over previous
//
#include <hip/hip_runtime.h>

#define BB 8
#define NN 2048
#define CC 128
#define KMAX 32
#define NEG 0.2f
#define CH 8
#define CHSZ (NN / CH)   // 256
#define CAP 32           // per-thread candidate buffer (u8 entries; drain-on-full keeps j order)

using bf16x8 = __attribute__((ext_vector_type(8))) short;  // 8 bf16 (4 VGPRs)
using f32x4  = __attribute__((ext_vector_type(4))) float;  // 4 fp32

// Map f32 to a u32 whose unsigned order == float order (handles negatives).
__device__ __forceinline__ unsigned int f2key(float f) {
  unsigned int b = __float_as_uint(f);
  return (b & 0x80000000u) ? ~b : (b | 0x80000000u);
}

// np-exact f32 squared norm: fl(fl(x^2+y^2)+z^2), no FMA contraction.
__device__ __forceinline__ float sq3(float x, float y, float z) {
  return __fadd_rn(__fadd_rn(__fmul_rn(x, x), __fmul_rn(y, y)), __fmul_rn(z, z));
}

// np-exact f32 distance key: d2 = fl( fl(sq_i+sq_j) - fl(2*dot) ).
__device__ __forceinline__ float d2np(float px, float py, float pz, float sqq,
                                      float qx, float qy, float qz, float sqj) {
  float dot = __fmaf_rn(pz, qz, __fmaf_rn(py, qy, __fmul_rn(px, qx)));
  return __fsub_rn(__fadd_rn(sqq, sqj), __fmul_rn(2.0f, dot));
}

// f32 -> bf16 (round to nearest even), finite inputs.
__device__ __forceinline__ unsigned short f2bf(float f) {
  unsigned int u = __float_as_uint(f);
  return (unsigned short)((u + 0x7fffu + ((u >> 16) & 1u)) >> 16);
}
// bf16 -> f32, exact.
__device__ __forceinline__ float bf2f(unsigned short u) {
  return __uint_as_float(((unsigned int)u) << 16);
}

// 8 consecutive f32 -> bf16x8 A-fragment (bit-identical to the old cvt_x+load).
__device__ __forceinline__ bf16x8 cvt8(const float* __restrict__ p) {
  float4 a = *(const float4*)(p);
  float4 b = *(const float4*)(p + 4);
  bf16x8 r;
  r[0] = (short)f2bf(a.x); r[1] = (short)f2bf(a.y);
  r[2] = (short)f2bf(a.z); r[3] = (short)f2bf(a.w);
  r[4] = (short)f2bf(b.x); r[5] = (short)f2bf(b.y);
  r[6] = (short)f2bf(b.z); r[7] = (short)f2bf(b.w);
  return r;
}

// XOR-swizzled LDS slot for point (chunk c, offset jj). Conflict-free for the
// 8-address broadcast pattern: bank quad = 4*((jj^c)&7), distinct over c.
__device__ __forceinline__ int paddr(int c, int jj) { return (c << 8) + (jj ^ c); }

// ---------------------------------------------------------------------------
// knn body v7 = R2-proven scan/select + in-block 8-lane SHUFFLE-TOURNAMENT
// merge. R7/R8's serial merge used hk[bc]/head[bc] dynamic register indexing
// -> scratch demotion (rule: runtime-indexed arrays go to local memory) =
// ~23us; the same pattern made standalone knn_p2 ~30us. This version keeps
// all merge state in SCALARS: packed u64 = (key<<11)|(c<<8)|jj, group-min via
// 3x shfl_xor (lanes of one query = its 8 chunk lists), winner alone advances
// with one LDS read. Packing preserves the exact tie rule (equal key ->
// lower c = lower j); low 11 bits ARE j = c*256+jj. nbr bytes identical to
// the original knn_p1+knn_p2 pipeline (sentinels never selected: >=32 real
// candidates gated per query).
// ---------------------------------------------------------------------------
__device__ __forceinline__ void knn_body(int bx, int tid,
                                         const float* __restrict__ pos,
                                         int* __restrict__ nbr,
                                         float4* __restrict__ sp4,
                                         unsigned char* __restrict__ sbuf) {
  int b = bx >> 6;                               // 64 blocks per batch
  int qbase = (bx & 63) * 32;
  const float* pb = pos + (size_t)b * NN * 3;
  for (int t = tid; t < NN; t += 256) {
    float xx = pb[t * 3 + 0];
    float yy = pb[t * 3 + 1];
    float zz = pb[t * 3 + 2];
    sp4[paddr(t >> 8, t & 255)] = make_float4(xx, yy, zz, sq3(xx, yy, zz));
  }
  __syncthreads();

  int q = qbase + (tid >> 3);
  int c = tid & 7;
  float4 pq = sp4[paddr(q >> 8, q & 255)];
  float px = pq.x, py = pq.y, pz = pq.z;
  float sqq = pq.w;
  int j0 = c * CHSZ;

  // ---- pass 1: per-chunk 4th-best via min/max insertion network (values only)
  const float SENT = 3.0e38f;                    // loses to every real d2
  float a0 = SENT, a1 = SENT, a2 = SENT, a3 = SENT;
#pragma unroll 4
  for (int jj = 0; jj < CHSZ; ++jj) {
    float4 pj = sp4[paddr(c, jj)];               // one ds_read_b128, 8-addr broadcast
    float d2 = d2np(px, py, pz, sqq, pj.x, pj.y, pj.z, pj.w);
    if (j0 + jj == q) d2 = SENT;                 // self never competes
    float m0 = fmaxf(a0, d2); a0 = fminf(a0, d2);
    float m1 = fmaxf(a1, m0); a1 = fminf(a1, m0);
    float m2 = fmaxf(a2, m1); a2 = fminf(a2, m1);
    a3 = fminf(a3, m2);
  }

  // ---- threshold: max of 4th-best over the 8 chunks of this query (intra-wave)
  float T = a3;
  T = fmaxf(T, __shfl_xor(T, 1));
  T = fmaxf(T, __shfl_xor(T, 2));
  T = fmaxf(T, __shfl_xor(T, 4));

  unsigned int ak[KMAX];
  int ai[KMAX];
#pragma unroll
  for (int k = 0; k < KMAX; ++k) { ak[k] = 0xFFFFFFFFu; ai[k] = 0xFFFF; }

  int sbase = tid * CAP;
  auto drain = [&](int cnt2) {
    for (int u = 0; u < cnt2; ++u) {
      int jj2 = (int)sbuf[sbase + u];
      int j = j0 + jj2;
      float4 pj = sp4[paddr(c, jj2)];
      float d2 = d2np(px, py, pz, sqq, pj.x, pj.y, pj.z, pj.w);
      unsigned int key = f2key(d2);               // self never buffered
      if (key < ak[KMAX - 1]) {                   // strict: stable ties -> lower j
#pragma unroll
        for (int k = KMAX - 1; k >= 1; --k) {
          bool ck  = key < ak[k];
          bool ckm = key < ak[k - 1];
          unsigned int tk = ckm ? ak[k - 1] : key;
          int          ti = ckm ? ai[k - 1] : j;
          ak[k] = ck ? tk : ak[k];
          ai[k] = ck ? ti : ai[k];
        }
        bool c0b = key < ak[0];
        ak[0] = c0b ? key : ak[0];
        ai[0] = c0b ? j : ai[0];
      }
    }
  };

  // ---- pass 2: gate d2 <= T (monotone-equivalent to key <= T_key), buffer jj
  int cnt = 0;
  for (int jj = 0; jj < CHSZ; ++jj) {
    float4 pj = sp4[paddr(c, jj)];
    float d2 = d2np(px, py, pz, sqq, pj.x, pj.y, pj.z, pj.w);
    bool pass = (d2 <= T) && (j0 + jj != q);
    if (pass) {
      if (cnt == CAP) { drain(CAP); cnt = 0; }   // rare; preserves j order
      sbuf[sbase + cnt] = (unsigned char)jj;
      ++cnt;
    }
  }
  drain(cnt);

  // ---- in-block merge: store lists to LDS (transposed [k][tid], conflict-
  // free), then 8-lane shuffle tournament per query. All state scalar.
  __syncthreads();                               // all drains done; LDS reusable
  unsigned int* mkey = (unsigned int*)sp4;       // [32k][256tid] u32 = 32 KB
  unsigned char* mjj = sbuf;                     // [32k][256tid] u8  =  8 KB
#pragma unroll
  for (int k = 0; k < KMAX; ++k) {
    mkey[k * 256 + tid] = ak[k];                 // lanes -> consecutive words
    mjj[k * 256 + tid] = (unsigned char)(ai[k] & 255);
  }
  __syncthreads();

  int hd = 0;
  unsigned long long packed =
      ((unsigned long long)ak[0] << 11) | (unsigned int)((c << 8) | (ai[0] & 255));
  int* onb = nbr + ((size_t)(b * NN + q)) * KMAX;
#pragma unroll
  for (int r = 0; r < KMAX; ++r) {
    unsigned long long m = packed;
    unsigned long long s1 = __shfl_xor(m, 1); m = m < s1 ? m : s1;
    unsigned long long s2 = __shfl_xor(m, 2); m = m < s2 ? m : s2;
    unsigned long long s4 = __shfl_xor(m, 4); m = m < s4 ? m : s4;
    if (c == 0) onb[r] = (int)(m & 0x7FF);       // j = c*256 + jj
    if (packed == m) {                           // unique winner (distinct c)
      ++hd;
      if (hd < KMAX) {
        unsigned int kv = mkey[hd * 256 + tid];
        unsigned int jv = mjj[hd * 256 + tid];
        packed = ((unsigned long long)kv << 11) | (unsigned int)((c << 8) | jv);
      } else {
        packed = ~0ull;                          // exhausted: never wins again
      }
    }
  }
}

// ---------------------------------------------------------------------------
// 6-proj MFMA body (on-the-fly x conversion), bf16 out.
// ---------------------------------------------------------------------------
__device__ __forceinline__ void proj_body(int z, int mx, int tid,
                                          const float* __restrict__ x,
                                          const unsigned short* __restrict__ wf,
                                          unsigned short* __restrict__ projb) {
  unsigned short* out = projb + (size_t)z * ((size_t)BB * NN * CC);
  int wave = tid >> 6;
  int lane = tid & 63;
  int m0 = (mx * 4 + wave) * 16;
  int quad = lane >> 4;
  int am = m0 + (lane & 15);

  f32x4 acc[8];
#pragma unroll
  for (int nt = 0; nt < 8; ++nt) acc[nt] = (f32x4){0.f, 0.f, 0.f, 0.f};

  const unsigned short* wz = wf + (size_t)z * (8 * 4 * 64 * 8);
#pragma unroll
  for (int ks = 0; ks < 4; ++ks) {
    bf16x8 a = cvt8(x + (size_t)am * CC + ks * 32 + quad * 8);
#pragma unroll
    for (int nt = 0; nt < 8; ++nt) {
      bf16x8 bfr = *(const bf16x8*)(wz + (size_t)(((nt * 4 + ks) * 64 + lane) * 8));
      acc[nt] = __builtin_amdgcn_mfma_f32_16x16x32_bf16(a, bfr, acc[nt], 0, 0, 0);
    }
  }

  int col0 = lane & 15;
#pragma unroll
  for (int nt = 0; nt < 8; ++nt)
#pragma unroll
    for (int r = 0; r < 4; ++r)
      out[(size_t)(m0 + quad * 4 + r) * CC + nt * 16 + col0] = f2bf(acc[nt][r]);
}

// ---------------------------------------------------------------------------
// Wg epilogue MFMA body (on-the-fly x conversion), f32 h out.
// ---------------------------------------------------------------------------
__device__ __forceinline__ void wg_body(int mx, int tid,
                                        const float* __restrict__ x,
                                        const float* __restrict__ pos,
                                        const unsigned short* __restrict__ wf,
                                        const float* __restrict__ wgtail,
                                        const float* __restrict__ bg,
                                        float* __restrict__ h) {
  int wave = tid >> 6;
  int lane = tid & 63;
  int m0 = (mx * 4 + wave) * 16;
  int quad = lane >> 4;
  int am = m0 + (lane & 15);

  f32x4 acc[8];
#pragma unroll
  for (int nt = 0; nt < 8; ++nt) acc[nt] = (f32x4){0.f, 0.f, 0.f, 0.f};

  const unsigned short* wz = wf + (size_t)6 * (8 * 4 * 64 * 8);
#pragma unroll
  for (int ks = 0; ks < 4; ++ks) {
    bf16x8 a = cvt8(x + (size_t)am * CC + ks * 32 + quad * 8);
#pragma unroll
    for (int nt = 0; nt < 8; ++nt) {
      bf16x8 b = *(const bf16x8*)(wz + (size_t)(((nt * 4 + ks) * 64 + lane) * 8));
      acc[nt] = __builtin_amdgcn_mfma_f32_16x16x32_bf16(a, b, acc[nt], 0, 0, 0);
    }
  }

  float posr[4][3];
#pragma unroll
  for (int r = 0; r < 4; ++r) {
    int m = m0 + quad * 4 + r;
    posr[r][0] = pos[m * 3 + 0];
    posr[r][1] = pos[m * 3 + 1];
    posr[r][2] = pos[m * 3 + 2];
  }

  int col0 = lane & 15;
#pragma unroll
  for (int nt = 0; nt < 8; ++nt) {
    int col = nt * 16 + col0;
    float bv = bg[col];
    float t0 = wgtail[col];
    float t1 = wgtail[CC + col];
    float t2 = wgtail[2 * CC + col];
#pragma unroll
    for (int r = 0; r < 4; ++r) {
      float v = acc[nt][r] + bv
              + posr[r][0] * t0 + posr[r][1] * t1 + posr[r][2] * t2;
      v = v > 0.f ? v : NEG * v;
      h[(size_t)(m0 + quad * 4 + r) * CC + col] = v;
    }
  }
}

// ---------------------------------------------------------------------------
// FUSED FRONT: blocks [0,512) = knn + shuffle merge (writes nbr);
// [512,2048) = 6-proj; [2048,2304) = Wg. LDS exactly 40,960 B.
// ---------------------------------------------------------------------------
__global__ __launch_bounds__(256) void fused_front(
    const float* __restrict__ pos,
    int* __restrict__ nbr,
    const float* __restrict__ x,
    const unsigned short* __restrict__ wf,
    unsigned short* __restrict__ projb,
    const float* __restrict__ wgtail,
    const float* __restrict__ bg,
    float* __restrict__ h) {
  __shared__ float4 sp4[CH * 256];               // 32,768 B (XOR-swizzled / merge keys)
  __shared__ unsigned char sbuf[256 * CAP];      // 8,192 B  (cand buf / merge jj)

  if (blockIdx.x < 512) {
    knn_body(blockIdx.x, threadIdx.x, pos, nbr, sp4, sbuf);
  } else if (blockIdx.x < 2048) {
    int bx = blockIdx.x - 512;
    proj_body(bx >> 8, bx & 255, threadIdx.x, x, wf, projb);
  } else {
    wg_body(blockIdx.x - 2048, threadIdx.x, x, pos, wf, wgtail, bg, h);
  }
}

// ---------------------------------------------------------------------------
// K1a (fallback only): knn standalone — same body, writes nbr directly.
// ---------------------------------------------------------------------------
__global__ __launch_bounds__(256) void knn_p1(const float* __restrict__ pos,
                                              int* __restrict__ nbr) {
  __shared__ float4 sp4[CH * 256];
  __shared__ unsigned char sbuf[256 * CAP];
  knn_body(blockIdx.x, threadIdx.x, pos, nbr, sp4, sbuf);
}

// ---------------------------------------------------------------------------
// K-wcvt: blocks [0,64): 8 weight matrices (f32) -> bf16 B-fragment order.
// Blocks [64,192): pos-projection pp[l][m][c] = pos_m . Wpos[l][:,c] (f32).
// ---------------------------------------------------------------------------
__global__ __launch_bounds__(256) void wcvt(const float* __restrict__ Wa,
                                            const float* __restrict__ Wb,
                                            const float* __restrict__ Wc,
                                            const float* __restrict__ Wgm,
                                            const float* __restrict__ W1m,
                                            unsigned short* __restrict__ wf,
                                            const float* __restrict__ Wpos,
                                            const float* __restrict__ pos,
                                            float* __restrict__ pp) {
  if (blockIdx.x < 64) {
    int t = blockIdx.x * 256 + threadIdx.x;      // 0 .. 16383
    int lane = t & 63;
    int ks = (t >> 6) & 3;
    int nt = (t >> 8) & 7;
    int z = t >> 11;
    const float* W = (z < 2) ? (Wa + (size_t)z * CC * CC)
                   : (z < 4) ? (Wb + (size_t)(z - 2) * CC * CC)
                   : (z < 6) ? (Wc + (size_t)(z - 4) * CC * CC)
                   : (z == 6) ? Wgm : W1m;
    int n = nt * 16 + (lane & 15);
    int kb = ks * 32 + (lane >> 4) * 8;
    unsigned short* o = wf + (size_t)t * 8;
#pragma unroll
    for (int j = 0; j < 8; ++j)
      o[j] = f2bf(W[(size_t)(kb + j) * CC + n]);
  } else {
    int pb2 = blockIdx.x - 64;                   // 0..127 -> 128 m-rows each
    int l = threadIdx.x >> 7;                    // layer 0/1
    int c = threadIdx.x & 127;
    const float* Wp = Wpos + (size_t)l * 3 * CC;
    float w0 = Wp[c], w1 = Wp[CC + c], w2 = Wp[2 * CC + c];
    float* ppl = pp + (size_t)l * ((size_t)BB * NN * CC);
    int m0 = pb2 * 128;
    for (int mi = 0; mi < 128; ++mi) {
      int m = m0 + mi;
      float xx = pos[m * 3 + 0];
      float yy = pos[m * 3 + 1];
      float zz = pos[m * 3 + 2];
      ppl[(size_t)m * CC + c] = __fmaf_rn(zz, w2, __fmaf_rn(yy, w1, __fmul_rn(xx, w0)));
    }
  }
}

// ---------------------------------------------------------------------------
// Fallback-only standalone wrappers for the two MFMA bodies.
// ---------------------------------------------------------------------------
__global__ __launch_bounds__(256) void proj_fly(const float* __restrict__ x,
                                                const unsigned short* __restrict__ wf,
                                                unsigned short* __restrict__ projb) {
  proj_body(blockIdx.z, blockIdx.x, threadIdx.x, x, wf, projb);
}
__global__ __launch_bounds__(256) void wg_fly(const float* __restrict__ x,
                                              const float* __restrict__ pos,
                                              const unsigned short* __restrict__ wf,
                                              const float* __restrict__ wgtail,
                                              const float* __restrict__ bg,
                                              float* __restrict__ h) {
  wg_body(blockIdx.x, threadIdx.x, x, pos, wf, wgtail, bg, h);
}

// ---------------------------------------------------------------------------
// K3: fused attention v3 (R7/R8-proven) — delta via precomputed pos-projection
// pp: del = pp_i - pp_j + bp. Block 128 = one point's channels.
// ---------------------------------------------------------------------------
__global__ __launch_bounds__(128) void attn2_kernel(
    const int* __restrict__ nbr,
    const unsigned short* __restrict__ s0, const unsigned short* __restrict__ v0,
    const unsigned short* __restrict__ t0,
    const unsigned short* __restrict__ s1, const unsigned short* __restrict__ v1,
    const unsigned short* __restrict__ t1,
    const float* __restrict__ pp, const float* __restrict__ bpos,
    const float* __restrict__ h, unsigned short* __restrict__ hb) {
  int b = blockIdx.x & 7;                        // XCD-locality swizzle
  int n = blockIdx.x >> 3;
  int bn = (b << 11) + n;
  int c = threadIdx.x;

  // batched neighbor-row load: 32 ints = 8 x int4 (nbr rows are 128B-aligned)
  const int* nb = nbr + (size_t)bn * KMAX;
  int idxs[KMAX];
#pragma unroll
  for (int u = 0; u < KMAX / 4; ++u) {
    int4 v4 = *(const int4*)(nb + u * 4);
    idxs[u * 4 + 0] = v4.x; idxs[u * 4 + 1] = v4.y;
    idxs[u * 4 + 2] = v4.z; idxs[u * 4 + 3] = v4.w;
  }

  float ht = h[(size_t)bn * CC + c];             // h_in (Wg output, f32)

#pragma unroll
  for (int l = 0; l < 2; ++l) {
    int dil = l + 1;
    const unsigned short* s = l ? s1 : s0;
    const unsigned short* v = l ? v1 : v0;
    const unsigned short* t = l ? t1 : t0;
    const float* ppl = pp + (size_t)l * ((size_t)BB * NN * CC);
    float bp = bpos[(size_t)l * CC + c];
    float tc = bf2f(t[(size_t)bn * CC + c]);
    float ppi = ppl[(size_t)bn * CC + c];

    // neighbor ids for this layer (compile-time indices -> registers)
    int id[17];
#pragma unroll
    for (int j = 0; j < 17; ++j) id[j] = (j < 16) ? idxs[j * dil] : n;

    // batched independent gathers: s (bf16) and pp (f32), coalesced rows
    float sc[17], pj[17];
#pragma unroll
    for (int j = 0; j < 17; ++j)
      sc[j] = bf2f(s[((size_t)(b * NN + id[j])) * CC + c]);
#pragma unroll
    for (int j = 0; j < 17; ++j)
      pj[j] = ppl[((size_t)(b * NN + id[j])) * CC + c];

    float alpha[17], del[17];
#pragma unroll
    for (int j = 0; j < 17; ++j) {
      float d = ppi - pj[j] + bp;
      del[j] = d;
      alpha[j] = tc - sc[j] + d;
    }
    // fmax tree (associative & commutative on finite floats)
    float m8[8];
#pragma unroll
    for (int j = 0; j < 8; ++j) m8[j] = fmaxf(alpha[j], alpha[j + 8]);
    float m4a = fmaxf(m8[0], m8[1]), m4b = fmaxf(m8[2], m8[3]);
    float m4c = fmaxf(m8[4], m8[5]), m4d = fmaxf(m8[6], m8[7]);
    float mx = fmaxf(fmaxf(fmaxf(m4a, m4b), fmaxf(m4c, m4d)), alpha[16]);

    float sum = 0.f;
#pragma unroll
    for (int j = 0; j < 17; ++j) {
      float w = __expf(alpha[j] - mx);
      alpha[j] = w;
      sum += w;
    }
    float inv = 1.f / sum;

    // batched independent v-gathers
    float vc[17];
#pragma unroll
    for (int j = 0; j < 17; ++j)
      vc[j] = bf2f(v[((size_t)(b * NN + id[j])) * CC + c]);

    float hc = 0.f;
#pragma unroll
    for (int j = 0; j < 17; ++j)
      hc += alpha[j] * (vc[j] + del[j]);
    ht += hc * inv;
  }

  hb[(size_t)bn * CC + c] = f2bf(ht);
}

// ---------------------------------------------------------------------------
// K4: W1 MFMA + final projection fused. Grid M/64 x 256.
// ---------------------------------------------------------------------------
__global__ __launch_bounds__(256) void mfma_w1_final(
    const unsigned short* __restrict__ hb,
    const unsigned short* __restrict__ wz,
    const float* __restrict__ b1,
    const float* __restrict__ W2,
    const float* __restrict__ b2,
    const float* __restrict__ pos,
    float* __restrict__ out) {
  int wave = threadIdx.x >> 6;
  int lane = threadIdx.x & 63;
  int m0 = (blockIdx.x * 4 + wave) * 16;
  int quad = lane >> 4;
  int am = m0 + (lane & 15);

  f32x4 acc[8];
#pragma unroll
  for (int nt = 0; nt < 8; ++nt) acc[nt] = (f32x4){0.f, 0.f, 0.f, 0.f};

#pragma unroll
  for (int ks = 0; ks < 4; ++ks) {
    bf16x8 a = *(const bf16x8*)(hb + (size_t)am * CC + ks * 32 + quad * 8);
#pragma unroll
    for (int nt = 0; nt < 8; ++nt) {
      bf16x8 b = *(const bf16x8*)(wz + (size_t)(((nt * 4 + ks) * 64 + lane) * 8));
      acc[nt] = __builtin_amdgcn_mfma_f32_16x16x32_bf16(a, b, acc[nt], 0, 0, 0);
    }
  }

  int col0 = lane & 15;
  float part[4][3];
#pragma unroll
  for (int r = 0; r < 4; ++r)
#pragma unroll
    for (int d = 0; d < 3; ++d) part[r][d] = 0.f;

#pragma unroll
  for (int nt = 0; nt < 8; ++nt) {
    int col = nt * 16 + col0;
    float bv = b1[col];
    float w20 = W2[col * 3 + 0];
    float w21 = W2[col * 3 + 1];
    float w22 = W2[col * 3 + 2];
#pragma unroll
    for (int r = 0; r < 4; ++r) {
      float gv = acc[nt][r] + bv;
      gv = gv > 0.f ? gv : NEG * gv;
      part[r][0] = fmaf(gv, w20, part[r][0]);
      part[r][1] = fmaf(gv, w21, part[r][1]);
      part[r][2] = fmaf(gv, w22, part[r][2]);
    }
  }

#pragma unroll
  for (int off = 8; off >= 1; off >>= 1) {
#pragma unroll
    for (int r = 0; r < 4; ++r)
#pragma unroll
      for (int d = 0; d < 3; ++d)
        part[r][d] += __shfl_xor(part[r][d], off);
  }

  if (col0 == 0) {
#pragma unroll
    for (int r = 0; r < 4; ++r) {
      int m = m0 + quad * 4 + r;
#pragma unroll
      for (int d = 0; d < 3; ++d)
        out[(size_t)m * 3 + d] = part[r][d] + b2[d] + pos[(size_t)m * 3 + d];
    }
  }
}

extern "C" void kernel_launch(void* const* d_in, const int* in_sizes, int n_in,
                              void* d_out, int out_size, void* d_ws, size_t ws_size,
                              hipStream_t stream) {
  const float* x     = (const float*)d_in[0];
  const float* pos   = (const float*)d_in[1];
  const float* W_lin = (const float*)d_in[2];
  const float* W_src = (const float*)d_in[3];
  const float* W_dst = (const float*)d_in[4];
  const float* W_pos = (const float*)d_in[5];
  const float* b_pos = (const float*)d_in[6];
  const float* Wg    = (const float*)d_in[7];
  const float* bg    = (const float*)d_in[8];
  const float* W1    = (const float*)d_in[9];
  const float* b1    = (const float*)d_in[10];
  const float* W2    = (const float*)d_in[11];
  const float* b2    = (const float*)d_in[12];
  float* out = (float*)d_out;

  const size_t M = (size_t)BB * NN;        // 16384
  const size_t MC = M * CC;                // 2,097,152

  // Layout (proven offsets preserved): nbr 2MB | cand slot (unused) | fb:
  //   projb (bf16, fb[0..3MC))  s0,s1,v0,v1,t0,t1
  //   (old candk slot fb[3MC..5MC) unused)
  //   h     (f32,  fb[5MC..6MC))
  //   pp    (f32,  fb[6MC..8MC))  2 layers x M x C pos-projection
  // hb at ws+BASE (4MB) | wf at ws+BASE+4MB (256KB).
  char* ws = (char*)d_ws;
  int* nbr = (int*)ws;
  unsigned short* cand = (unsigned short*)(ws + M * KMAX * sizeof(int));
  float* fb = (float*)(ws + M * KMAX * sizeof(int) + M * CH * KMAX * sizeof(unsigned short));
  unsigned short* projb = (unsigned short*)fb;
  unsigned short* sb0 = projb + 0 * MC;
  unsigned short* sb1 = projb + 1 * MC;
  unsigned short* vb0 = projb + 2 * MC;
  unsigned short* vb1 = projb + 3 * MC;
  unsigned short* tb0 = projb + 4 * MC;
  unsigned short* tb1 = projb + 5 * MC;
  float* h = fb + 5 * MC;
  float* pp = fb + 6 * MC;                 // 16 MB pos-projection

  const size_t BASE = M * KMAX * sizeof(int) + M * CH * KMAX * sizeof(unsigned short)
                    + 8 * MC * sizeof(float);                 // proven offset
  const size_t XB_BYTES = MC * sizeof(unsigned short);        // 4 MB (hb slot)
  const size_t WF_BYTES = 8 * 16384 * sizeof(unsigned short); // 256 KB
  const size_t FRAG = (size_t)(8 * 4 * 64 * 8);               // bf16 elems per weight
  bool fused_ok = ws_size >= BASE + XB_BYTES + WF_BYTES;

  if (fused_ok) {
    unsigned short* hb = (unsigned short*)(ws + BASE);
    unsigned short* wf = (unsigned short*)(ws + BASE + XB_BYTES);

    // 1. weight fragments + pos-projection (one small kernel)
    wcvt<<<192, 256, 0, stream>>>(W_src, W_lin, W_dst, Wg, W1, wf, W_pos, pos, pp);
    // 2. knn(+shuffle merge->nbr) [0,512) + 6-proj [512,2048) + Wg-epi [2048,2304)
    fused_front<<<2304, 256, 0, stream>>>(pos, nbr, x, wf, projb,
                                          Wg + 128 * CC, bg, h);
    // 3. attention (pp-based delta); writes hb = bf16(h_out)
    attn2_kernel<<<M, 128, 0, stream>>>(nbr, sb0, vb0, tb0,
                                        sb1, vb1, tb1, pp, b_pos, h, hb);
    // 4. g = leaky(h@W1+b1) via MFMA, then W2 reduce + b2 + pos, fused
    mfma_w1_final<<<M / 64, 256, 0, stream>>>(hb, wf + 7 * FRAG, b1,
                                              W2, b2, pos, out);
  } else {
    // Fallback: sequential, same numerics. hb/wf alias cand slot (unused).
    unsigned short* hb = cand;
    unsigned short* wf = cand + MC;
    knn_p1<<<512, 256, 0, stream>>>(pos, nbr);
    wcvt<<<192, 256, 0, stream>>>(W_src, W_lin, W_dst, Wg, W1, wf, W_pos, pos, pp);
    proj_fly<<<dim3(256, 1, 6), 256, 0, stream>>>(x, wf, projb);
    wg_fly<<<256, 256, 0, stream>>>(x, pos, wf, Wg + 128 * CC, bg, h);
    attn2_kernel<<<M, 128, 0, stream>>>(nbr, sb0, vb0, tb0,
                                        sb1, vb1, tb1, pp, b_pos, h, hb);
    mfma_w1_final<<<M / 64, 256, 0, stream>>>(hb, wf + 7 * FRAG, b1,
                                              W2, b2, pos, out);
  }
}

// Round 11
// 193.322 us; speedup vs baseline: 1.1401x; 1.0179x over previous
//
#include <hip/hip_runtime.h>

#define BB 8
#define NN 2048
#define CC 128
#define KMAX 32
#define NEG 0.2f
#define CH 8
#define CHSZ (NN / CH)   // 256
#define CAP 32           // per-thread candidate buffer (u8 entries; drain-on-full keeps j order)

using bf16x8 = __attribute__((ext_vector_type(8))) short;  // 8 bf16 (4 VGPRs)
using f32x4  = __attribute__((ext_vector_type(4))) float;  // 4 fp32

// Map f32 to a u32 whose unsigned order == float order (handles negatives).
__device__ __forceinline__ unsigned int f2key(float f) {
  unsigned int b = __float_as_uint(f);
  return (b & 0x80000000u) ? ~b : (b | 0x80000000u);
}

// np-exact f32 squared norm: fl(fl(x^2+y^2)+z^2), no FMA contraction.
__device__ __forceinline__ float sq3(float x, float y, float z) {
  return __fadd_rn(__fadd_rn(__fmul_rn(x, x), __fmul_rn(y, y)), __fmul_rn(z, z));
}

// np-exact f32 distance key: d2 = fl( fl(sq_i+sq_j) - fl(2*dot) ).
__device__ __forceinline__ float d2np(float px, float py, float pz, float sqq,
                                      float qx, float qy, float qz, float sqj) {
  float dot = __fmaf_rn(pz, qz, __fmaf_rn(py, qy, __fmul_rn(px, qx)));
  return __fsub_rn(__fadd_rn(sqq, sqj), __fmul_rn(2.0f, dot));
}

// f32 -> bf16 (round to nearest even), finite inputs.
__device__ __forceinline__ unsigned short f2bf(float f) {
  unsigned int u = __float_as_uint(f);
  return (unsigned short)((u + 0x7fffu + ((u >> 16) & 1u)) >> 16);
}
// bf16 -> f32, exact.
__device__ __forceinline__ float bf2f(unsigned short u) {
  return __uint_as_float(((unsigned int)u) << 16);
}

// 8 consecutive f32 -> bf16x8 A-fragment (bit-identical to the old cvt_x+load).
__device__ __forceinline__ bf16x8 cvt8(const float* __restrict__ p) {
  float4 a = *(const float4*)(p);
  float4 b = *(const float4*)(p + 4);
  bf16x8 r;
  r[0] = (short)f2bf(a.x); r[1] = (short)f2bf(a.y);
  r[2] = (short)f2bf(a.z); r[3] = (short)f2bf(a.w);
  r[4] = (short)f2bf(b.x); r[5] = (short)f2bf(b.y);
  r[6] = (short)f2bf(b.z); r[7] = (short)f2bf(b.w);
  return r;
}

// XOR-swizzled LDS slot for point (chunk c, offset jj). Conflict-free for the
// 8-address broadcast pattern: bank quad = 4*((jj^c)&7), distinct over c.
__device__ __forceinline__ int paddr(int c, int jj) { return (c << 8) + (jj ^ c); }

// ---------------------------------------------------------------------------
// knn body (R10-proven, ff=72us): R2 scan/select + in-block 8-lane SHUFFLE-
// TOURNAMENT merge (all scalar state; packed u64 = (key<<11)|j preserves the
// exact tie rule). nbr bytes identical to the original knn_p1+knn_p2.
// ---------------------------------------------------------------------------
__device__ __forceinline__ void knn_body(int bx, int tid,
                                         const float* __restrict__ pos,
                                         int* __restrict__ nbr,
                                         float4* __restrict__ sp4,
                                         unsigned char* __restrict__ sbuf) {
  int b = bx >> 6;                               // 64 blocks per batch
  int qbase = (bx & 63) * 32;
  const float* pb = pos + (size_t)b * NN * 3;
  for (int t = tid; t < NN; t += 256) {
    float xx = pb[t * 3 + 0];
    float yy = pb[t * 3 + 1];
    float zz = pb[t * 3 + 2];
    sp4[paddr(t >> 8, t & 255)] = make_float4(xx, yy, zz, sq3(xx, yy, zz));
  }
  __syncthreads();

  int q = qbase + (tid >> 3);
  int c = tid & 7;
  float4 pq = sp4[paddr(q >> 8, q & 255)];
  float px = pq.x, py = pq.y, pz = pq.z;
  float sqq = pq.w;
  int j0 = c * CHSZ;

  // ---- pass 1: per-chunk 4th-best via min/max insertion network (values only)
  const float SENT = 3.0e38f;                    // loses to every real d2
  float a0 = SENT, a1 = SENT, a2 = SENT, a3 = SENT;
#pragma unroll 4
  for (int jj = 0; jj < CHSZ; ++jj) {
    float4 pj = sp4[paddr(c, jj)];               // one ds_read_b128, 8-addr broadcast
    float d2 = d2np(px, py, pz, sqq, pj.x, pj.y, pj.z, pj.w);
    if (j0 + jj == q) d2 = SENT;                 // self never competes
    float m0 = fmaxf(a0, d2); a0 = fminf(a0, d2);
    float m1 = fmaxf(a1, m0); a1 = fminf(a1, m0);
    float m2 = fmaxf(a2, m1); a2 = fminf(a2, m1);
    a3 = fminf(a3, m2);
  }

  // ---- threshold: max of 4th-best over the 8 chunks of this query (intra-wave)
  float T = a3;
  T = fmaxf(T, __shfl_xor(T, 1));
  T = fmaxf(T, __shfl_xor(T, 2));
  T = fmaxf(T, __shfl_xor(T, 4));

  unsigned int ak[KMAX];
  int ai[KMAX];
#pragma unroll
  for (int k = 0; k < KMAX; ++k) { ak[k] = 0xFFFFFFFFu; ai[k] = 0xFFFF; }

  int sbase = tid * CAP;
  auto drain = [&](int cnt2) {
    for (int u = 0; u < cnt2; ++u) {
      int jj2 = (int)sbuf[sbase + u];
      int j = j0 + jj2;
      float4 pj = sp4[paddr(c, jj2)];
      float d2 = d2np(px, py, pz, sqq, pj.x, pj.y, pj.z, pj.w);
      unsigned int key = f2key(d2);               // self never buffered
      if (key < ak[KMAX - 1]) {                   // strict: stable ties -> lower j
#pragma unroll
        for (int k = KMAX - 1; k >= 1; --k) {
          bool ck  = key < ak[k];
          bool ckm = key < ak[k - 1];
          unsigned int tk = ckm ? ak[k - 1] : key;
          int          ti = ckm ? ai[k - 1] : j;
          ak[k] = ck ? tk : ak[k];
          ai[k] = ck ? ti : ai[k];
        }
        bool c0b = key < ak[0];
        ak[0] = c0b ? key : ak[0];
        ai[0] = c0b ? j : ai[0];
      }
    }
  };

  // ---- pass 2: gate d2 <= T (monotone-equivalent to key <= T_key), buffer jj
  int cnt = 0;
  for (int jj = 0; jj < CHSZ; ++jj) {
    float4 pj = sp4[paddr(c, jj)];
    float d2 = d2np(px, py, pz, sqq, pj.x, pj.y, pj.z, pj.w);
    bool pass = (d2 <= T) && (j0 + jj != q);
    if (pass) {
      if (cnt == CAP) { drain(CAP); cnt = 0; }   // rare; preserves j order
      sbuf[sbase + cnt] = (unsigned char)jj;
      ++cnt;
    }
  }
  drain(cnt);

  // ---- in-block merge: store lists to LDS (transposed [k][tid], conflict-
  // free), then 8-lane shuffle tournament per query. All state scalar.
  __syncthreads();                               // all drains done; LDS reusable
  unsigned int* mkey = (unsigned int*)sp4;       // [32k][256tid] u32 = 32 KB
  unsigned char* mjj = sbuf;                     // [32k][256tid] u8  =  8 KB
#pragma unroll
  for (int k = 0; k < KMAX; ++k) {
    mkey[k * 256 + tid] = ak[k];                 // lanes -> consecutive words
    mjj[k * 256 + tid] = (unsigned char)(ai[k] & 255);
  }
  __syncthreads();

  int hd = 0;
  unsigned long long packed =
      ((unsigned long long)ak[0] << 11) | (unsigned int)((c << 8) | (ai[0] & 255));
  int* onb = nbr + ((size_t)(b * NN + q)) * KMAX;
#pragma unroll
  for (int r = 0; r < KMAX; ++r) {
    unsigned long long m = packed;
    unsigned long long s1 = __shfl_xor(m, 1); m = m < s1 ? m : s1;
    unsigned long long s2 = __shfl_xor(m, 2); m = m < s2 ? m : s2;
    unsigned long long s4 = __shfl_xor(m, 4); m = m < s4 ? m : s4;
    if (c == 0) onb[r] = (int)(m & 0x7FF);       // j = c*256 + jj
    if (packed == m) {                           // unique winner (distinct c)
      ++hd;
      if (hd < KMAX) {
        unsigned int kv = mkey[hd * 256 + tid];
        unsigned int jv = mjj[hd * 256 + tid];
        packed = ((unsigned long long)kv << 11) | (unsigned int)((c << 8) | jv);
      } else {
        packed = ~0ull;                          // exhausted: never wins again
      }
    }
  }
}

// ---------------------------------------------------------------------------
// 6-proj MFMA body, bf16 out with s/v INTERLEAVED layout:
//   u16 units from pb16 base: z=0 (s0) -> idx*2      in sv0 region [0,2MC)
//                             z=2 (v0) -> idx*2+1
//                             z=1 (s1) -> 2MC+idx*2  in sv1 region [2MC,4MC)
//                             z=3 (v1) -> 2MC+idx*2+1
//                             z=4 (t0) -> 4MC+idx ;  z=5 (t1) -> 5MC+idx
// Same bf16 bits as the old separate buffers; only placement changes.
// ---------------------------------------------------------------------------
__device__ __forceinline__ void proj_body(int z, int mx, int tid,
                                          const float* __restrict__ x,
                                          const unsigned short* __restrict__ wf,
                                          unsigned short* __restrict__ pb16) {
  const size_t MCSZ = (size_t)BB * NN * CC;
  size_t base;
  int mul;
  if (z < 4) {
    base = (size_t)(z & 1) * 2 * MCSZ + (size_t)(z >> 1);  // +1 for v (z=2,3)
    mul = 2;
  } else {
    base = (size_t)z * MCSZ;                                // 4MC / 5MC
    mul = 1;
  }
  int wave = tid >> 6;
  int lane = tid & 63;
  int m0 = (mx * 4 + wave) * 16;
  int quad = lane >> 4;
  int am = m0 + (lane & 15);

  f32x4 acc[8];
#pragma unroll
  for (int nt = 0; nt < 8; ++nt) acc[nt] = (f32x4){0.f, 0.f, 0.f, 0.f};

  const unsigned short* wz = wf + (size_t)z * (8 * 4 * 64 * 8);
#pragma unroll
  for (int ks = 0; ks < 4; ++ks) {
    bf16x8 a = cvt8(x + (size_t)am * CC + ks * 32 + quad * 8);
#pragma unroll
    for (int nt = 0; nt < 8; ++nt) {
      bf16x8 bfr = *(const bf16x8*)(wz + (size_t)(((nt * 4 + ks) * 64 + lane) * 8));
      acc[nt] = __builtin_amdgcn_mfma_f32_16x16x32_bf16(a, bfr, acc[nt], 0, 0, 0);
    }
  }

  int col0 = lane & 15;
#pragma unroll
  for (int nt = 0; nt < 8; ++nt)
#pragma unroll
    for (int r = 0; r < 4; ++r) {
      size_t idx = (size_t)(m0 + quad * 4 + r) * CC + nt * 16 + col0;
      pb16[base + idx * mul] = f2bf(acc[nt][r]);
    }
}

// ---------------------------------------------------------------------------
// Wg epilogue MFMA body (on-the-fly x conversion), f32 h out.
// ---------------------------------------------------------------------------
__device__ __forceinline__ void wg_body(int mx, int tid,
                                        const float* __restrict__ x,
                                        const float* __restrict__ pos,
                                        const unsigned short* __restrict__ wf,
                                        const float* __restrict__ wgtail,
                                        const float* __restrict__ bg,
                                        float* __restrict__ h) {
  int wave = tid >> 6;
  int lane = tid & 63;
  int m0 = (mx * 4 + wave) * 16;
  int quad = lane >> 4;
  int am = m0 + (lane & 15);

  f32x4 acc[8];
#pragma unroll
  for (int nt = 0; nt < 8; ++nt) acc[nt] = (f32x4){0.f, 0.f, 0.f, 0.f};

  const unsigned short* wz = wf + (size_t)6 * (8 * 4 * 64 * 8);
#pragma unroll
  for (int ks = 0; ks < 4; ++ks) {
    bf16x8 a = cvt8(x + (size_t)am * CC + ks * 32 + quad * 8);
#pragma unroll
    for (int nt = 0; nt < 8; ++nt) {
      bf16x8 b = *(const bf16x8*)(wz + (size_t)(((nt * 4 + ks) * 64 + lane) * 8));
      acc[nt] = __builtin_amdgcn_mfma_f32_16x16x32_bf16(a, b, acc[nt], 0, 0, 0);
    }
  }

  float posr[4][3];
#pragma unroll
  for (int r = 0; r < 4; ++r) {
    int m = m0 + quad * 4 + r;
    posr[r][0] = pos[m * 3 + 0];
    posr[r][1] = pos[m * 3 + 1];
    posr[r][2] = pos[m * 3 + 2];
  }

  int col0 = lane & 15;
#pragma unroll
  for (int nt = 0; nt < 8; ++nt) {
    int col = nt * 16 + col0;
    float bv = bg[col];
    float t0 = wgtail[col];
    float t1 = wgtail[CC + col];
    float t2 = wgtail[2 * CC + col];
#pragma unroll
    for (int r = 0; r < 4; ++r) {
      float v = acc[nt][r] + bv
              + posr[r][0] * t0 + posr[r][1] * t1 + posr[r][2] * t2;
      v = v > 0.f ? v : NEG * v;
      h[(size_t)(m0 + quad * 4 + r) * CC + col] = v;
    }
  }
}

// ---------------------------------------------------------------------------
// FUSED FRONT: blocks [0,512) = knn + shuffle merge (writes nbr);
// [512,2048) = 6-proj (interleaved sv); [2048,2304) = Wg. LDS 40,960 B.
// ---------------------------------------------------------------------------
__global__ __launch_bounds__(256) void fused_front(
    const float* __restrict__ pos,
    int* __restrict__ nbr,
    const float* __restrict__ x,
    const unsigned short* __restrict__ wf,
    unsigned short* __restrict__ pb16,
    const float* __restrict__ wgtail,
    const float* __restrict__ bg,
    float* __restrict__ h) {
  __shared__ float4 sp4[CH * 256];               // 32,768 B (XOR-swizzled / merge keys)
  __shared__ unsigned char sbuf[256 * CAP];      // 8,192 B  (cand buf / merge jj)

  if (blockIdx.x < 512) {
    knn_body(blockIdx.x, threadIdx.x, pos, nbr, sp4, sbuf);
  } else if (blockIdx.x < 2048) {
    int bx = blockIdx.x - 512;
    proj_body(bx >> 8, bx & 255, threadIdx.x, x, wf, pb16);
  } else {
    wg_body(blockIdx.x - 2048, threadIdx.x, x, pos, wf, wgtail, bg, h);
  }
}

// ---------------------------------------------------------------------------
// K1a (fallback only): knn standalone — same body, writes nbr directly.
// ---------------------------------------------------------------------------
__global__ __launch_bounds__(256) void knn_p1(const float* __restrict__ pos,
                                              int* __restrict__ nbr) {
  __shared__ float4 sp4[CH * 256];
  __shared__ unsigned char sbuf[256 * CAP];
  knn_body(blockIdx.x, threadIdx.x, pos, nbr, sp4, sbuf);
}

// ---------------------------------------------------------------------------
// K-wcvt: blocks [0,64): 8 weight matrices (f32) -> bf16 B-fragment order.
// Blocks [64,192): pos-projection pp[l][m][c] = pos_m . Wpos[l][:,c] (f32).
// ---------------------------------------------------------------------------
__global__ __launch_bounds__(256) void wcvt(const float* __restrict__ Wa,
                                            const float* __restrict__ Wb,
                                            const float* __restrict__ Wc,
                                            const float* __restrict__ Wgm,
                                            const float* __restrict__ W1m,
                                            unsigned short* __restrict__ wf,
                                            const float* __restrict__ Wpos,
                                            const float* __restrict__ pos,
                                            float* __restrict__ pp) {
  if (blockIdx.x < 64) {
    int t = blockIdx.x * 256 + threadIdx.x;      // 0 .. 16383
    int lane = t & 63;
    int ks = (t >> 6) & 3;
    int nt = (t >> 8) & 7;
    int z = t >> 11;
    const float* W = (z < 2) ? (Wa + (size_t)z * CC * CC)
                   : (z < 4) ? (Wb + (size_t)(z - 2) * CC * CC)
                   : (z < 6) ? (Wc + (size_t)(z - 4) * CC * CC)
                   : (z == 6) ? Wgm : W1m;
    int n = nt * 16 + (lane & 15);
    int kb = ks * 32 + (lane >> 4) * 8;
    unsigned short* o = wf + (size_t)t * 8;
#pragma unroll
    for (int j = 0; j < 8; ++j)
      o[j] = f2bf(W[(size_t)(kb + j) * CC + n]);
  } else {
    int pb2 = blockIdx.x - 64;                   // 0..127 -> 128 m-rows each
    int l = threadIdx.x >> 7;                    // layer 0/1
    int c = threadIdx.x & 127;
    const float* Wp = Wpos + (size_t)l * 3 * CC;
    float w0 = Wp[c], w1 = Wp[CC + c], w2 = Wp[2 * CC + c];
    float* ppl = pp + (size_t)l * ((size_t)BB * NN * CC);
    int m0 = pb2 * 128;
    for (int mi = 0; mi < 128; ++mi) {
      int m = m0 + mi;
      float xx = pos[m * 3 + 0];
      float yy = pos[m * 3 + 1];
      float zz = pos[m * 3 + 2];
      ppl[(size_t)m * CC + c] = __fmaf_rn(zz, w2, __fmaf_rn(yy, w1, __fmul_rn(xx, w0)));
    }
  }
}

// ---------------------------------------------------------------------------
// Fallback-only standalone wrappers for the two MFMA bodies.
// ---------------------------------------------------------------------------
__global__ __launch_bounds__(256) void proj_fly(const float* __restrict__ x,
                                                const unsigned short* __restrict__ wf,
                                                unsigned short* __restrict__ pb16) {
  proj_body(blockIdx.z, blockIdx.x, threadIdx.x, x, wf, pb16);
}
__global__ __launch_bounds__(256) void wg_fly(const float* __restrict__ x,
                                              const float* __restrict__ pos,
                                              const unsigned short* __restrict__ wf,
                                              const float* __restrict__ wgtail,
                                              const float* __restrict__ bg,
                                              float* __restrict__ h) {
  wg_body(blockIdx.x, threadIdx.x, x, pos, wf, wgtail, bg, h);
}

// ---------------------------------------------------------------------------
// K3: fused attention v4 — s/v packed as one u32 per neighbor (s low16, v
// high16): one dword gather replaces two bf16 gathers (34 fewer VMEM/thread).
// delta via precomputed pp: del = pp_i - pp_j + bp. Numerics identical to v3
// (same bf16 bits, same op order). Block 128 = one point's channels.
// ---------------------------------------------------------------------------
__global__ __launch_bounds__(128) void attn2_kernel(
    const int* __restrict__ nbr,
    const unsigned int* __restrict__ sv0, const unsigned int* __restrict__ sv1,
    const unsigned short* __restrict__ t0, const unsigned short* __restrict__ t1,
    const float* __restrict__ pp, const float* __restrict__ bpos,
    const float* __restrict__ h, unsigned short* __restrict__ hb) {
  int b = blockIdx.x & 7;                        // XCD-locality swizzle
  int n = blockIdx.x >> 3;
  int bn = (b << 11) + n;
  int c = threadIdx.x;

  // batched neighbor-row load: 32 ints = 8 x int4 (nbr rows are 128B-aligned)
  const int* nb = nbr + (size_t)bn * KMAX;
  int idxs[KMAX];
#pragma unroll
  for (int u = 0; u < KMAX / 4; ++u) {
    int4 v4 = *(const int4*)(nb + u * 4);
    idxs[u * 4 + 0] = v4.x; idxs[u * 4 + 1] = v4.y;
    idxs[u * 4 + 2] = v4.z; idxs[u * 4 + 3] = v4.w;
  }

  float ht = h[(size_t)bn * CC + c];             // h_in (Wg output, f32)

#pragma unroll
  for (int l = 0; l < 2; ++l) {
    int dil = l + 1;
    const unsigned int* sv = l ? sv1 : sv0;
    const unsigned short* t = l ? t1 : t0;
    const float* ppl = pp + (size_t)l * ((size_t)BB * NN * CC);
    float bp = bpos[(size_t)l * CC + c];
    float tc = bf2f(t[(size_t)bn * CC + c]);
    float ppi = ppl[(size_t)bn * CC + c];

    // neighbor ids for this layer (compile-time indices -> registers)
    int id[17];
#pragma unroll
    for (int j = 0; j < 17; ++j) id[j] = (j < 16) ? idxs[j * dil] : n;

    // batched independent gathers: packed s|v (u32) and pp (f32), coalesced
    unsigned int svw[17];
    float pj[17];
#pragma unroll
    for (int j = 0; j < 17; ++j)
      svw[j] = sv[((size_t)(b * NN + id[j])) * CC + c];
#pragma unroll
    for (int j = 0; j < 17; ++j)
      pj[j] = ppl[((size_t)(b * NN + id[j])) * CC + c];

    float alpha[17], del[17];
#pragma unroll
    for (int j = 0; j < 17; ++j) {
      float d = ppi - pj[j] + bp;
      del[j] = d;
      float sc = bf2f((unsigned short)(svw[j] & 0xFFFFu));
      alpha[j] = tc - sc + d;
    }
    // fmax tree (associative & commutative on finite floats)
    float m8[8];
#pragma unroll
    for (int j = 0; j < 8; ++j) m8[j] = fmaxf(alpha[j], alpha[j + 8]);
    float m4a = fmaxf(m8[0], m8[1]), m4b = fmaxf(m8[2], m8[3]);
    float m4c = fmaxf(m8[4], m8[5]), m4d = fmaxf(m8[6], m8[7]);
    float mx = fmaxf(fmaxf(fmaxf(m4a, m4b), fmaxf(m4c, m4d)), alpha[16]);

    float sum = 0.f;
#pragma unroll
    for (int j = 0; j < 17; ++j) {
      float w = __expf(alpha[j] - mx);
      alpha[j] = w;
      sum += w;
    }
    float inv = 1.f / sum;

    float hc = 0.f;
#pragma unroll
    for (int j = 0; j < 17; ++j) {
      float vc = bf2f((unsigned short)(svw[j] >> 16));
      hc += alpha[j] * (vc + del[j]);
    }
    ht += hc * inv;
  }

  hb[(size_t)bn * CC + c] = f2bf(ht);
}

// ---------------------------------------------------------------------------
// K4: W1 MFMA + final projection fused. Grid M/64 x 256.
// ---------------------------------------------------------------------------
__global__ __launch_bounds__(256) void mfma_w1_final(
    const unsigned short* __restrict__ hb,
    const unsigned short* __restrict__ wz,
    const float* __restrict__ b1,
    const float* __restrict__ W2,
    const float* __restrict__ b2,
    const float* __restrict__ pos,
    float* __restrict__ out) {
  int wave = threadIdx.x >> 6;
  int lane = threadIdx.x & 63;
  int m0 = (blockIdx.x * 4 + wave) * 16;
  int quad = lane >> 4;
  int am = m0 + (lane & 15);

  f32x4 acc[8];
#pragma unroll
  for (int nt = 0; nt < 8; ++nt) acc[nt] = (f32x4){0.f, 0.f, 0.f, 0.f};

#pragma unroll
  for (int ks = 0; ks < 4; ++ks) {
    bf16x8 a = *(const bf16x8*)(hb + (size_t)am * CC + ks * 32 + quad * 8);
#pragma unroll
    for (int nt = 0; nt < 8; ++nt) {
      bf16x8 b = *(const bf16x8*)(wz + (size_t)(((nt * 4 + ks) * 64 + lane) * 8));
      acc[nt] = __builtin_amdgcn_mfma_f32_16x16x32_bf16(a, b, acc[nt], 0, 0, 0);
    }
  }

  int col0 = lane & 15;
  float part[4][3];
#pragma unroll
  for (int r = 0; r < 4; ++r)
#pragma unroll
    for (int d = 0; d < 3; ++d) part[r][d] = 0.f;

#pragma unroll
  for (int nt = 0; nt < 8; ++nt) {
    int col = nt * 16 + col0;
    float bv = b1[col];
    float w20 = W2[col * 3 + 0];
    float w21 = W2[col * 3 + 1];
    float w22 = W2[col * 3 + 2];
#pragma unroll
    for (int r = 0; r < 4; ++r) {
      float gv = acc[nt][r] + bv;
      gv = gv > 0.f ? gv : NEG * gv;
      part[r][0] = fmaf(gv, w20, part[r][0]);
      part[r][1] = fmaf(gv, w21, part[r][1]);
      part[r][2] = fmaf(gv, w22, part[r][2]);
    }
  }

#pragma unroll
  for (int off = 8; off >= 1; off >>= 1) {
#pragma unroll
    for (int r = 0; r < 4; ++r)
#pragma unroll
      for (int d = 0; d < 3; ++d)
        part[r][d] += __shfl_xor(part[r][d], off);
  }

  if (col0 == 0) {
#pragma unroll
    for (int r = 0; r < 4; ++r) {
      int m = m0 + quad * 4 + r;
#pragma unroll
      for (int d = 0; d < 3; ++d)
        out[(size_t)m * 3 + d] = part[r][d] + b2[d] + pos[(size_t)m * 3 + d];
    }
  }
}

extern "C" void kernel_launch(void* const* d_in, const int* in_sizes, int n_in,
                              void* d_out, int out_size, void* d_ws, size_t ws_size,
                              hipStream_t stream) {
  const float* x     = (const float*)d_in[0];
  const float* pos   = (const float*)d_in[1];
  const float* W_lin = (const float*)d_in[2];
  const float* W_src = (const float*)d_in[3];
  const float* W_dst = (const float*)d_in[4];
  const float* W_pos = (const float*)d_in[5];
  const float* b_pos = (const float*)d_in[6];
  const float* Wg    = (const float*)d_in[7];
  const float* bg    = (const float*)d_in[8];
  const float* W1    = (const float*)d_in[9];
  const float* b1    = (const float*)d_in[10];
  const float* W2    = (const float*)d_in[11];
  const float* b2    = (const float*)d_in[12];
  float* out = (float*)d_out;

  const size_t M = (size_t)BB * NN;        // 16384
  const size_t MC = M * CC;                // 2,097,152

  // Layout (proven offsets preserved): nbr 2MB | cand slot (unused) | fb:
  //   pb16 region (fb[0..3MC) floats = 12MC bytes):
  //     sv0 u32[MC] | sv1 u32[MC] | t0 u16[MC] | t1 u16[MC]
  //   (old candk slot fb[3MC..5MC) unused)
  //   h     (f32,  fb[5MC..6MC))
  //   pp    (f32,  fb[6MC..8MC))  2 layers x M x C pos-projection
  // hb at ws+BASE (4MB) | wf at ws+BASE+4MB (256KB).
  char* ws = (char*)d_ws;
  int* nbr = (int*)ws;
  unsigned short* cand = (unsigned short*)(ws + M * KMAX * sizeof(int));
  float* fb = (float*)(ws + M * KMAX * sizeof(int) + M * CH * KMAX * sizeof(unsigned short));
  unsigned short* pb16 = (unsigned short*)fb;
  unsigned int* sv0 = (unsigned int*)pb16;            // [0, 2MC) u16 units
  unsigned int* sv1 = sv0 + MC;                       // [2MC, 4MC)
  unsigned short* tb0 = pb16 + 4 * MC;                // [4MC, 5MC)
  unsigned short* tb1 = pb16 + 5 * MC;                // [5MC, 6MC)
  float* h = fb + 5 * MC;
  float* pp = fb + 6 * MC;                 // 16 MB pos-projection

  const size_t BASE = M * KMAX * sizeof(int) + M * CH * KMAX * sizeof(unsigned short)
                    + 8 * MC * sizeof(float);                 // proven offset
  const size_t XB_BYTES = MC * sizeof(unsigned short);        // 4 MB (hb slot)
  const size_t WF_BYTES = 8 * 16384 * sizeof(unsigned short); // 256 KB
  const size_t FRAG = (size_t)(8 * 4 * 64 * 8);               // bf16 elems per weight
  bool fused_ok = ws_size >= BASE + XB_BYTES + WF_BYTES;

  if (fused_ok) {
    unsigned short* hb = (unsigned short*)(ws + BASE);
    unsigned short* wf = (unsigned short*)(ws + BASE + XB_BYTES);

    // 1. weight fragments + pos-projection (one small kernel)
    wcvt<<<192, 256, 0, stream>>>(W_src, W_lin, W_dst, Wg, W1, wf, W_pos, pos, pp);
    // 2. knn(+shuffle merge->nbr) [0,512) + 6-proj [512,2048) + Wg-epi [2048,2304)
    fused_front<<<2304, 256, 0, stream>>>(pos, nbr, x, wf, pb16,
                                          Wg + 128 * CC, bg, h);
    // 3. attention (packed s|v gathers + pp delta); writes hb = bf16(h_out)
    attn2_kernel<<<M, 128, 0, stream>>>(nbr, sv0, sv1, tb0, tb1,
                                        pp, b_pos, h, hb);
    // 4. g = leaky(h@W1+b1) via MFMA, then W2 reduce + b2 + pos, fused
    mfma_w1_final<<<M / 64, 256, 0, stream>>>(hb, wf + 7 * FRAG, b1,
                                              W2, b2, pos, out);
  } else {
    // Fallback: sequential, same numerics. hb/wf alias cand slot (unused).
    unsigned short* hb = cand;
    unsigned short* wf = cand + MC;
    knn_p1<<<512, 256, 0, stream>>>(pos, nbr);
    wcvt<<<192, 256, 0, stream>>>(W_src, W_lin, W_dst, Wg, W1, wf, W_pos, pos, pp);
    proj_fly<<<dim3(256, 1, 6), 256, 0, stream>>>(x, wf, pb16);
    wg_fly<<<256, 256, 0, stream>>>(x, pos, wf, Wg + 128 * CC, bg, h);
    attn2_kernel<<<M, 128, 0, stream>>>(nbr, sv0, sv1, tb0, tb1,
                                        pp, b_pos, h, hb);
    mfma_w1_final<<<M / 64, 256, 0, stream>>>(hb, wf + 7 * FRAG, b1,
                                              W2, b2, pos, out);
  }
}